// Round 9
// baseline (99.602 us; speedup 1.0000x reference)
//
#include <hip/hip_runtime.h>

// Depth rasterization, MI355X — round 9.
// R8 post-mortem: scalar-path walk took (VGPR 12 / SGPR 64 / LDS 0), raster
// 48->41.8us, but VALUBusy fell to 41% (VALU time ~17us).  Remaining wall =
// exposed s_load latency: every 2-face iter is ctz -> s_load x8 -> lgkm wait
// (~250cyc) -> ~120cyc VALU, duty ~32%/wave.  Fix: software-pipeline the
// survivor walk — issue iteration k+1's scalar loads BEFORE computing
// iteration k (manual rotate; compiler places the lgkm wait after the
// compute).  Load latency overlaps compute; TLP covers the rest.
// Math path unchanged: bit-identical to numpy (contract off, reference op
// order, s=+-1 folds exact, single deferred IEEE divide per pixel).

#pragma clang fp contract(off)

#define H_OUT 128
#define W_OUT 128
#define NV 778
#define NF 1538
#define NB 4
#define NCHUNK 25
#define NFP (NCHUNK * 64)          // 1600 padded faces per batch
#define BG100 0x42C80000u          // 100.0f bits (uint order == float order >0)

// data record (16 floats / 64B):
// [0]s*dx12 [1]s*dy12 [2]s*dx02 [3]s*dy02 [4]s*dx01 [5]s*dy01
// [6]x0 [7]y0 [8]x1 [9]y1 [10]x2 [11]y2  [12]z0 [13]z1 [14]z2 [15]s*area
// bbox record (4 floats): xmin, xmax, ymin, ymax  (pad: inverted -> culled)

__global__ __launch_bounds__(256) void prep_kernel(
    const float* __restrict__ verts,   // [NB][NV][3]
    const int* __restrict__ faces,     // [NF][3]
    float* __restrict__ bbox,          // [NB*NFP][4]
    float* __restrict__ data,          // [NB*NFP][16]
    unsigned int* __restrict__ outu)   // [NB*16384]
{
    int t = blockIdx.x * 256 + threadIdx.x;   // grid 256 blocks = 65536
    outu[t] = BG100;                           // init z-buffer to 100.0f
    if (t >= NB * NFP) return;
    int b = t / NFP;
    int f = t - b * NFP;
    float* bb = bbox + (size_t)t * 4;
    if (f >= NF) {                             // pad face: always culled
        bb[0] = 1e30f; bb[1] = -1e30f; bb[2] = 1e30f; bb[3] = -1e30f;
        return;
    }
    int i0 = faces[f * 3 + 0];
    int i1 = faces[f * 3 + 1];
    int i2 = faces[f * 3 + 2];
    const float* vb = verts + (size_t)b * NV * 3;
    float x0 = vb[i0 * 3 + 0], y0 = vb[i0 * 3 + 1], z0 = vb[i0 * 3 + 2];
    float x1 = vb[i1 * 3 + 0], y1 = vb[i1 * 3 + 1], z1 = vb[i1 * 3 + 2];
    float x2 = vb[i2 * 3 + 0], y2 = vb[i2 * 3 + 1], z2 = vb[i2 * 3 + 2];

    // Reference deltas (single RN subtracts) and area (reference op order).
    float dx12 = x2 - x1, dy12 = y2 - y1;
    float dx02 = x0 - x2, dy02 = y0 - y2;
    float dx01 = x1 - x0, dy01 = y1 - y0;
    float y20 = y2 - y0, x20 = x2 - x0;
    float area = dx01 * y20 - dy01 * x20;

    float s = 0.0f;
    if (fabsf(area) > 1e-12f) s = (area > 0.0f) ? 1.0f : -1.0f;

    float xmin = fminf(fminf(x0, x1), x2), xmax = fmaxf(fmaxf(x0, x1), x2);
    float ymin = fminf(fminf(y0, y1), y2), ymax = fmaxf(fmaxf(y0, y1), y2);
    if (s == 0.0f) { xmin = 1e30f; xmax = -1e30f; }  // degenerate -> culled

    bb[0] = xmin; bb[1] = xmax; bb[2] = ymin; bb[3] = ymax;

    float* o = data + (size_t)t * 16;
    o[0] = s * dx12; o[1] = s * dy12;        // exact sign folds (s = +-1)
    o[2] = s * dx02; o[3] = s * dy02;
    o[4] = s * dx01; o[5] = s * dy01;
    o[6] = x0;  o[7] = y0;  o[8] = x1;  o[9] = y1;  o[10] = x2; o[11] = y2;
    o[12] = z0; o[13] = z1; o[14] = z2; o[15] = s * area;   // = |area| > 0
}

__global__ __launch_bounds__(128) void raster_kernel(
    const float* __restrict__ bbox,    // [NB*NFP][4]
    const float* __restrict__ data,    // [NB*NFP][16]
    unsigned int* __restrict__ outu)   // [NB*16384], init 100.0f bits
{
    int blk = blockIdx.x;              // 12800 = chunk(25) x batch(4) x tile(128)
    int tile  = blk & 127;             // 16x8-px tiles: 8 across, 16 down
    int b     = (blk >> 7) & 3;
    int chunk = blk >> 9;
    int tid = threadIdx.x;             // 128 threads = 2 waves, no coupling
    int lane = tid & 63;
    int w = __builtin_amdgcn_readfirstlane(tid >> 6);   // wave id 0/1

    int tx = tile & 7, ty = tile >> 3;
    int i = ty * 8 + w * 4 + (lane >> 4);   // output row (wave: 4 rows)
    int j = tx * 16 + (lane & 15);          // output col
    float px = 5.0f * (float)j + 2.5f;
    float py = 5.0f * (float)i + 2.5f;

    // Wave-uniform cull extents (wave covers 4 rows -> 15 render px span).
    float px_lo = 80.0f * (float)tx + 2.5f, px_hi = px_lo + 75.0f;
    float py_lo = 40.0f * (float)ty + 20.0f * (float)w + 2.5f;
    float py_hi = py_lo + 15.0f;

    // Lane-parallel bbox cull -> 64-bit survivor mask (one VMEM float4).
    int gbase = b * NFP + chunk * 64;
    float4 bb = *(const float4*)&bbox[(size_t)(gbase + lane) * 4];
    bool ov = !(bb.x > px_hi || bb.y < px_lo || bb.z > py_hi || bb.w < py_lo);
    unsigned long long mask = __ballot(ov);

    float nb = 1e10f, ab = 1.0f;

    // ---- software-pipelined survivor walk (2 faces/stage, 1 stage ahead) ----
    bool have = (mask != 0ull);
    int f0 = 0, f1 = 0;
    if (have) {
        f0 = __builtin_ctzll(mask); mask &= mask - 1;
        f1 = mask ? __builtin_ctzll(mask) : f0;       // dup last if odd:
        mask &= mask - 1;                             // idempotent under <
    }
    // Prologue: load current pair (scalar path: wave-uniform index).
    int u0 = __builtin_amdgcn_readfirstlane(f0);
    int u1 = __builtin_amdgcn_readfirstlane(f1);
    const float4* p0 = (const float4*)(data + (size_t)(gbase + u0) * 16);
    const float4* p1 = (const float4*)(data + (size_t)(gbase + u1) * 16);
    float4 A0 = p0[0], B0 = p0[1], C0 = p0[2], D0 = p0[3];
    float4 A1 = p1[0], B1 = p1[1], C1 = p1[2], D1 = p1[3];

    while (have) {
        // Extract next pair and ISSUE its loads before computing current.
        bool haveN = (mask != 0ull);
        int g0 = f0, g1 = f1;          // default: reload current (never used)
        if (haveN) {
            g0 = __builtin_ctzll(mask); mask &= mask - 1;
            g1 = mask ? __builtin_ctzll(mask) : g0;
            mask &= mask - 1;
        }
        int v0 = __builtin_amdgcn_readfirstlane(g0);
        int v1 = __builtin_amdgcn_readfirstlane(g1);
        const float4* q0 = (const float4*)(data + (size_t)(gbase + v0) * 16);
        const float4* q1 = (const float4*)(data + (size_t)(gbase + v1) * 16);
        float4 NA0 = q0[0], NB0 = q0[1], NC0 = q0[2], ND0 = q0[3];
        float4 NA1 = q1[0], NB1 = q1[1], NC1 = q1[2], ND1 = q1[3];

        // Compute current pair (no dependency on the new loads -> the lgkm
        // wait lands after this block).
        // face 0 (bit-exact reference op order; s folded in prep)
        float e0 = A0.x * (py - C0.y) - A0.y * (px - C0.x);
        float e1 = A0.z * (py - C0.w) - A0.w * (px - C0.z);
        float e2 = B0.x * (py - B0.w) - B0.y * (px - B0.z);
        bool in0 = (e0 >= 0.0f) & (e1 >= 0.0f) & (e2 >= 0.0f);
        float n0 = ((e0 * D0.x) + (e1 * D0.y)) + (e2 * D0.z);
        bool t0 = in0 & (n0 * ab < nb * D0.w);   // cross-mult min (all >=0)
        nb = t0 ? n0 : nb;  ab = t0 ? D0.w : ab;

        // face 1
        float h0 = A1.x * (py - C1.y) - A1.y * (px - C1.x);
        float h1 = A1.z * (py - C1.w) - A1.w * (px - C1.z);
        float h2 = B1.x * (py - B1.w) - B1.y * (px - B1.z);
        bool in1 = (h0 >= 0.0f) & (h1 >= 0.0f) & (h2 >= 0.0f);
        float n1 = ((h0 * D1.x) + (h1 * D1.y)) + (h2 * D1.z);
        bool t1 = in1 & (n1 * ab < nb * D1.w);
        nb = t1 ? n1 : nb;  ab = t1 ? D1.w : ab;

        // Rotate pipeline.
        A0 = NA0; B0 = NB0; C0 = NC0; D0 = ND0;
        A1 = NA1; B1 = NB1; C1 = NC1; D1 = ND1;
        have = haveN;
    }

    float z = nb / ab;                 // winner: bit-exact reference quotient
    z += 0.0f;                         // -0.0 -> +0.0 for uint ordering
    if (z < 1e9f)                      // no-hit sentinel (1e10) -> keep bg 100
        atomicMin(&outu[(size_t)b * (H_OUT * W_OUT) + i * W_OUT + j],
                  __float_as_uint(fminf(z, 100.0f)));
}

extern "C" void kernel_launch(void* const* d_in, const int* in_sizes, int n_in,
                              void* d_out, int out_size, void* d_ws, size_t ws_size,
                              hipStream_t stream) {
    const float* verts = (const float*)d_in[0];   // [4][778][3] f32
    const int*   faces = (const int*)d_in[1];     // [1538][3] i32
    float* out = (float*)d_out;                   // [4][128][128] f32
    float* bbox = (float*)d_ws;                   // 4*1600*4  floats = 100 KB
    float* data = bbox + (size_t)NB * NFP * 4;    // 4*1600*16 floats = 400 KB

    prep_kernel<<<256, 256, 0, stream>>>(verts, faces, bbox, data,
                                         (unsigned int*)out);
    raster_kernel<<<NCHUNK * NB * 128, 128, 0, stream>>>(
        bbox, data, (unsigned int*)out);
}

// Round 10
// 97.019 us; speedup vs baseline: 1.0266x; 1.0266x over previous
//
#include <hip/hip_runtime.h>

// Depth rasterization, MI355X — round 10.
// R9 post-mortem: manual SW-pipelining HURT (41.8->49us) — rotate = ~32
// scalar s_movs + branches per iter on the same scalar pipe as the loads.
// Reverted to R8 loop shape.  R8 model: 2-face iter = 8 s_load (250cyc
// latency) + ~120cyc VALU for 64px -> 32% duty.  Fix: amortize the SAME
// loads over 4 pixels/lane (wave = 16x16 output tile, 80x80 render window).
// Survivors/chunk +~20% (window grows 75x15->80x80 vs ~320px-mean bboxes)
// but VALU/iter x4 (~450cyc > 250cyc latency) -> duty ~85%.  Single-wave
// 64-thr blocks (6400) for finest drain granularity.
// Per-pixel math unchanged & independent (reference op order, contract off,
// s=+-1 folds exact, cross-mult min, one deferred IEEE divide per pixel).

#pragma clang fp contract(off)

#define H_OUT 128
#define W_OUT 128
#define NV 778
#define NF 1538
#define NB 4
#define NCHUNK 25
#define NFP (NCHUNK * 64)          // 1600 padded faces per batch
#define BG100 0x42C80000u          // 100.0f bits (uint order == float order >0)

// data record (16 floats / 64B):
// [0]s*dx12 [1]s*dy12 [2]s*dx02 [3]s*dy02 [4]s*dx01 [5]s*dy01
// [6]x0 [7]y0 [8]x1 [9]y1 [10]x2 [11]y2  [12]z0 [13]z1 [14]z2 [15]s*area
// bbox record (4 floats): xmin, xmax, ymin, ymax  (pad: inverted -> culled)

__global__ __launch_bounds__(256) void prep_kernel(
    const float* __restrict__ verts,   // [NB][NV][3]
    const int* __restrict__ faces,     // [NF][3]
    float* __restrict__ bbox,          // [NB*NFP][4]
    float* __restrict__ data,          // [NB*NFP][16]
    unsigned int* __restrict__ outu)   // [NB*16384]
{
    int t = blockIdx.x * 256 + threadIdx.x;   // grid 256 blocks = 65536
    outu[t] = BG100;                           // init z-buffer to 100.0f
    if (t >= NB * NFP) return;
    int b = t / NFP;
    int f = t - b * NFP;
    float* bb = bbox + (size_t)t * 4;
    if (f >= NF) {                             // pad face: always culled
        bb[0] = 1e30f; bb[1] = -1e30f; bb[2] = 1e30f; bb[3] = -1e30f;
        return;
    }
    int i0 = faces[f * 3 + 0];
    int i1 = faces[f * 3 + 1];
    int i2 = faces[f * 3 + 2];
    const float* vb = verts + (size_t)b * NV * 3;
    float x0 = vb[i0 * 3 + 0], y0 = vb[i0 * 3 + 1], z0 = vb[i0 * 3 + 2];
    float x1 = vb[i1 * 3 + 0], y1 = vb[i1 * 3 + 1], z1 = vb[i1 * 3 + 2];
    float x2 = vb[i2 * 3 + 0], y2 = vb[i2 * 3 + 1], z2 = vb[i2 * 3 + 2];

    // Reference deltas (single RN subtracts) and area (reference op order).
    float dx12 = x2 - x1, dy12 = y2 - y1;
    float dx02 = x0 - x2, dy02 = y0 - y2;
    float dx01 = x1 - x0, dy01 = y1 - y0;
    float y20 = y2 - y0, x20 = x2 - x0;
    float area = dx01 * y20 - dy01 * x20;

    float s = 0.0f;
    if (fabsf(area) > 1e-12f) s = (area > 0.0f) ? 1.0f : -1.0f;

    float xmin = fminf(fminf(x0, x1), x2), xmax = fmaxf(fmaxf(x0, x1), x2);
    float ymin = fminf(fminf(y0, y1), y2), ymax = fmaxf(fmaxf(y0, y1), y2);
    if (s == 0.0f) { xmin = 1e30f; xmax = -1e30f; }  // degenerate -> culled

    bb[0] = xmin; bb[1] = xmax; bb[2] = ymin; bb[3] = ymax;

    float* o = data + (size_t)t * 16;
    o[0] = s * dx12; o[1] = s * dy12;        // exact sign folds (s = +-1)
    o[2] = s * dx02; o[3] = s * dy02;
    o[4] = s * dx01; o[5] = s * dy01;
    o[6] = x0;  o[7] = y0;  o[8] = x1;  o[9] = y1;  o[10] = x2; o[11] = y2;
    o[12] = z0; o[13] = z1; o[14] = z2; o[15] = s * area;   // = |area| > 0
}

__global__ __launch_bounds__(64) void raster_kernel(
    const float* __restrict__ bbox,    // [NB*NFP][4]
    const float* __restrict__ data,    // [NB*NFP][16]
    unsigned int* __restrict__ outu)   // [NB*16384], init 100.0f bits
{
    int blk = blockIdx.x;              // 6400 = chunk(25) x batch(4) x tile(64)
    int tile  = blk & 63;              // 16x16-px tiles: 8 across, 8 down
    int b     = (blk >> 6) & 3;
    int chunk = blk >> 8;
    int lane = threadIdx.x;            // 64 threads = 1 wave

    int tx = tile & 7, ty = tile >> 3;
    int col = lane & 15;               // output col within tile
    int rg  = lane >> 4;               // row group 0..3; lane rows: rg + 4k
    int j = tx * 16 + col;
    int i0r = ty * 16 + rg;            // row for k=0
    float px  = 5.0f * (float)j + 2.5f;
    float py0 = 5.0f * (float)i0r + 2.5f;   // k: py0 + 20k (exact fp32)

    // Wave-uniform cull window: full 16x16 tile (80x80 render px span 75).
    float px_lo = 80.0f * (float)tx + 2.5f, px_hi = px_lo + 75.0f;
    float py_lo = 80.0f * (float)ty + 2.5f, py_hi = py_lo + 75.0f;

    // Lane-parallel bbox cull -> 64-bit survivor mask (one VMEM float4).
    int gbase = b * NFP + chunk * 64;
    float4 bb = *(const float4*)&bbox[(size_t)(gbase + lane) * 4];
    bool ov = !(bb.x > px_hi || bb.y < px_lo || bb.z > py_hi || bb.w < py_lo);
    unsigned long long mask = __ballot(ov);

    float nb0 = 1e10f, ab0 = 1.0f;     // per-pixel (k) cross-mult min state
    float nb1 = 1e10f, ab1 = 1.0f;
    float nb2 = 1e10f, ab2 = 1.0f;
    float nb3 = 1e10f, ab3 = 1.0f;

    // Survivor walk, 2 faces/iter, 4 pixels/lane.  Face index wave-uniform
    // (scalar mask) -> readfirstlane -> s_load_dwordx4 x8 from K$; ~450cyc
    // of VALU per iteration hides the ~250cyc load latency.
    while (mask) {
        int f0 = __builtin_ctzll(mask); mask &= mask - 1;
        int f1 = mask ? __builtin_ctzll(mask) : f0;   // dup last if odd:
        mask &= mask - 1;                             // idempotent under <

        int u0 = __builtin_amdgcn_readfirstlane(f0);
        int u1 = __builtin_amdgcn_readfirstlane(f1);
        const float4* p0 = (const float4*)(data + (size_t)(gbase + u0) * 16);
        const float4* p1 = (const float4*)(data + (size_t)(gbase + u1) * 16);
        float4 A0 = p0[0], B0 = p0[1], C0 = p0[2], D0 = p0[3];
        float4 A1 = p1[0], B1 = p1[1], C1 = p1[2], D1 = p1[3];

        #pragma unroll
        for (int k = 0; k < 4; ++k) {
            float py = py0 + 20.0f * (float)k;   // exact (multiples of 2.5)
            float* nbp = (k == 0) ? &nb0 : (k == 1) ? &nb1 : (k == 2) ? &nb2 : &nb3;
            float* abp = (k == 0) ? &ab0 : (k == 1) ? &ab1 : (k == 2) ? &ab2 : &ab3;
            float nb = *nbp, ab = *abp;

            // face 0 (bit-exact reference op order; s folded in prep)
            float e0 = A0.x * (py - C0.y) - A0.y * (px - C0.x);
            float e1 = A0.z * (py - C0.w) - A0.w * (px - C0.z);
            float e2 = B0.x * (py - B0.w) - B0.y * (px - B0.z);
            bool in0 = (e0 >= 0.0f) & (e1 >= 0.0f) & (e2 >= 0.0f);
            float n0 = ((e0 * D0.x) + (e1 * D0.y)) + (e2 * D0.z);
            bool t0 = in0 & (n0 * ab < nb * D0.w);   // cross-mult min (>=0)
            nb = t0 ? n0 : nb;  ab = t0 ? D0.w : ab;

            // face 1
            float h0 = A1.x * (py - C1.y) - A1.y * (px - C1.x);
            float h1 = A1.z * (py - C1.w) - A1.w * (px - C1.z);
            float h2 = B1.x * (py - B1.w) - B1.y * (px - B1.z);
            bool in1 = (h0 >= 0.0f) & (h1 >= 0.0f) & (h2 >= 0.0f);
            float n1 = ((h0 * D1.x) + (h1 * D1.y)) + (h2 * D1.z);
            bool t1 = in1 & (n1 * ab < nb * D1.w);
            nb = t1 ? n1 : nb;  ab = t1 ? D1.w : ab;

            *nbp = nb; *abp = ab;
        }
    }

    // Epilogue: one IEEE divide + atomic per pixel (4 per lane).
    unsigned int* slot0 = &outu[(size_t)b * (H_OUT * W_OUT) + i0r * W_OUT + j];
    #pragma unroll
    for (int k = 0; k < 4; ++k) {
        float nb = (k == 0) ? nb0 : (k == 1) ? nb1 : (k == 2) ? nb2 : nb3;
        float ab = (k == 0) ? ab0 : (k == 1) ? ab1 : (k == 2) ? ab2 : ab3;
        float z = nb / ab;             // winner: bit-exact reference quotient
        z += 0.0f;                     // -0.0 -> +0.0 for uint ordering
        if (z < 1e9f)                  // no-hit sentinel (1e10) -> keep bg 100
            atomicMin(slot0 + k * 4 * W_OUT, __float_as_uint(fminf(z, 100.0f)));
    }
}

extern "C" void kernel_launch(void* const* d_in, const int* in_sizes, int n_in,
                              void* d_out, int out_size, void* d_ws, size_t ws_size,
                              hipStream_t stream) {
    const float* verts = (const float*)d_in[0];   // [4][778][3] f32
    const int*   faces = (const int*)d_in[1];     // [1538][3] i32
    float* out = (float*)d_out;                   // [4][128][128] f32
    float* bbox = (float*)d_ws;                   // 4*1600*4  floats = 100 KB
    float* data = bbox + (size_t)NB * NFP * 4;    // 4*1600*16 floats = 400 KB

    prep_kernel<<<256, 256, 0, stream>>>(verts, faces, bbox, data,
                                         (unsigned int*)out);
    raster_kernel<<<NCHUNK * NB * 64, 64, 0, stream>>>(
        bbox, data, (unsigned int*)out);
}